// Round 2
// baseline (809.011 us; speedup 1.0000x reference)
//
#include <hip/hip_runtime.h>
#include <hip/hip_bf16.h>

#define DIN 512
#define DOUT 64

typedef float float4v __attribute__((ext_vector_type(4)));

// ---------------------------------------------------------------------------
// Kernel 1: support = leaky_relu(X @ W, 0.2)   (f32 in, f32 out)
// Each thread owns 1 row x 32 cols. W rows are wave-uniform -> scalar loads,
// inner loop is 32 v_fmac with SGPR src. Block = 256 thr = 128 rows x 64 cols.
// ---------------------------------------------------------------------------
__global__ __launch_bounds__(256) void gemm_lrelu_kernel(
    const float* __restrict__ X, const float* __restrict__ W,
    float* __restrict__ sup, int N)
{
  const int t    = threadIdx.x;
  const int wave = t >> 6;
  const int lane = t & 63;
  // col half (0 or 32); wave-uniform -> force SGPR so W loads scalarize
  const int h = __builtin_amdgcn_readfirstlane((wave & 1) * 32);
  const int row  = blockIdx.x * 128 + (wave >> 1) * 64 + lane;
  const int rowr = row < N ? row : N - 1;

  float acc[32];
#pragma unroll
  for (int c = 0; c < 32; ++c) acc[c] = 0.0f;

  const float* __restrict__ xrow = X + (size_t)rowr * DIN;

#pragma unroll 1
  for (int k = 0; k < DIN; k += 4) {
    const float4v xv = *reinterpret_cast<const float4v*>(xrow + k);
#pragma unroll
    for (int kk = 0; kk < 4; ++kk) {
      const float* __restrict__ wk = W + (k + kk) * DOUT + h;  // uniform addr
      const float xs = xv[kk];
#pragma unroll
      for (int c = 0; c < 32; ++c) acc[c] = fmaf(wk[c], xs, acc[c]);
    }
  }

  if (row < N) {
    float* __restrict__ o = sup + (size_t)row * DOUT + h;
#pragma unroll
    for (int c = 0; c < 32; ++c) {
      const float v = acc[c];
      o[c] = v > 0.0f ? v : 0.2f * v;
    }
  }
}

// ---------------------------------------------------------------------------
// Kernel 2: COO SpMM via atomics: out[rows[e]] += vals[e] * x[cols[e]]
// One edge per wave (64 lanes = 64 feature dims). Edge scalars batched 4-wide
// through SGPR loads. f32 accumulation in a pre-zeroed buffer.
// ---------------------------------------------------------------------------
__global__ __launch_bounds__(256) void spmm_atomic_kernel(
    const int* __restrict__ er, const int* __restrict__ ec,
    const float* __restrict__ ev, const float* __restrict__ x,
    float* __restrict__ out, int E)
{
  const int lane = threadIdx.x & 63;
  const int wid  = blockIdx.x * (blockDim.x >> 6) + (threadIdx.x >> 6);
  const int nw   = gridDim.x * (blockDim.x >> 6);

  for (int e = wid * 4; e < E; e += nw * 4) {
    const int es = __builtin_amdgcn_readfirstlane(e);
#pragma unroll
    for (int i = 0; i < 4; ++i) {
      if (es + i < E) {
        const int   r = er[es + i];
        const int   c = ec[es + i];
        const float v = ev[es + i];
        const float xv = x[(size_t)c * DOUT + lane];
        unsafeAtomicAdd(out + (size_t)r * DOUT + lane, v * xv);
      }
    }
  }
}

// ---------------------------------------------------------------------------
// Launch: memset d_out -> gemm(ws=support) -> spmm(support -> out0=output)
//         -> spmm(out0 -> out1=az).  All f32, no conversion (output dtype is
//         float32 per the reference).
// ws usage: N*64 f32 = 25.6 MB
// ---------------------------------------------------------------------------
extern "C" void kernel_launch(void* const* d_in, const int* in_sizes, int n_in,
                              void* d_out, int out_size, void* d_ws, size_t ws_size,
                              hipStream_t stream)
{
  const float* X  = (const float*)d_in[0];
  const float* W  = (const float*)d_in[1];
  const int*   er = (const int*)d_in[2];
  const int*   ec = (const int*)d_in[3];
  const float* ev = (const float*)d_in[4];

  const int N = in_sizes[0] / DIN;
  const int E = in_sizes[2];
  const size_t half = (size_t)N * DOUT;   // 6.4M elements

  float* sup = (float*)d_ws;              // support f32
  float* out0 = (float*)d_out;            // output f32
  float* out1 = out0 + half;              // az f32

  // zero both output accumulators (harness doesn't re-poison between replays)
  hipMemsetAsync(d_out, 0, (size_t)out_size * sizeof(float), stream);

  // support = leaky_relu(X @ W)
  gemm_lrelu_kernel<<<(N + 127) / 128, 256, 0, stream>>>(X, W, sup, N);

  // output = A @ support
  spmm_atomic_kernel<<<2048, 256, 0, stream>>>(er, ec, ev, sup, out0, E);

  // az = A @ output
  spmm_atomic_kernel<<<2048, 256, 0, stream>>>(er, ec, ev, out0, out1, E);
}

// Round 3
// 445.110 us; speedup vs baseline: 1.8176x; 1.8176x over previous
//
#include <hip/hip_runtime.h>
#include <hip/hip_bf16.h>

#define DIN 512
#define DOUT 64

typedef float float4v __attribute__((ext_vector_type(4)));

// ---------------------------------------------------------------------------
// Kernel 1: support = leaky_relu(X @ W, 0.2)   (f32 in, f32 out)  [unchanged]
// ---------------------------------------------------------------------------
__global__ __launch_bounds__(256) void gemm_lrelu_kernel(
    const float* __restrict__ X, const float* __restrict__ W,
    float* __restrict__ sup, int N)
{
  const int t    = threadIdx.x;
  const int wave = t >> 6;
  const int lane = t & 63;
  const int h = __builtin_amdgcn_readfirstlane((wave & 1) * 32);
  const int row  = blockIdx.x * 128 + (wave >> 1) * 64 + lane;
  const int rowr = row < N ? row : N - 1;

  float acc[32];
#pragma unroll
  for (int c = 0; c < 32; ++c) acc[c] = 0.0f;

  const float* __restrict__ xrow = X + (size_t)rowr * DIN;

#pragma unroll 1
  for (int k = 0; k < DIN; k += 4) {
    const float4v xv = *reinterpret_cast<const float4v*>(xrow + k);
#pragma unroll
    for (int kk = 0; kk < 4; ++kk) {
      const float* __restrict__ wk = W + (k + kk) * DOUT + h;
      const float xs = xv[kk];
#pragma unroll
      for (int c = 0; c < 32; ++c) acc[c] = fmaf(wk[c], xs, acc[c]);
    }
  }

  if (row < N) {
    float* __restrict__ o = sup + (size_t)row * DOUT + h;
#pragma unroll
    for (int c = 0; c < 32; ++c) {
      const float v = acc[c];
      o[c] = v > 0.0f ? v : 0.2f * v;
    }
  }
}

// ---------------------------------------------------------------------------
// CSR build: histogram -> exclusive scan (3 kernels) -> scatter
// ---------------------------------------------------------------------------
__global__ __launch_bounds__(256) void hist_kernel(
    const int* __restrict__ er, int* __restrict__ cnt, int E)
{
  int i = blockIdx.x * blockDim.x + threadIdx.x;
  const int stride = gridDim.x * blockDim.x;
  for (; i < E; i += stride) atomicAdd(&cnt[er[i]], 1);
}

// exclusive scan of 256-elem chunks; block sums out
__global__ __launch_bounds__(256) void scan_block_kernel(
    const int* __restrict__ in, int* __restrict__ out,
    int* __restrict__ bsum, int n)
{
  __shared__ int s[256];
  const int t = threadIdx.x;
  const int gid = blockIdx.x * 256 + t;
  const int v = gid < n ? in[gid] : 0;
  s[t] = v;
  __syncthreads();
#pragma unroll
  for (int off = 1; off < 256; off <<= 1) {
    const int add = t >= off ? s[t - off] : 0;
    __syncthreads();
    s[t] += add;
    __syncthreads();
  }
  if (gid < n) out[gid] = s[t] - v;          // exclusive
  if (t == 255) bsum[blockIdx.x] = s[255];   // chunk total
}

// single-block exclusive scan of the block sums (nb <= a few hundred)
__global__ __launch_bounds__(256) void scan_bsums_kernel(int* __restrict__ bsum, int nb)
{
  __shared__ int s[256];
  __shared__ int carry_s;
  const int t = threadIdx.x;
  if (t == 0) carry_s = 0;
  __syncthreads();
  for (int base = 0; base < nb; base += 256) {
    const int i = base + t;
    const int v = i < nb ? bsum[i] : 0;
    s[t] = v;
    __syncthreads();
#pragma unroll
    for (int off = 1; off < 256; off <<= 1) {
      const int add = t >= off ? s[t - off] : 0;
      __syncthreads();
      s[t] += add;
      __syncthreads();
    }
    const int carry = carry_s;
    if (i < nb) bsum[i] = s[t] - v + carry;  // exclusive + carry
    const int total = s[255];
    __syncthreads();
    if (t == 0) carry_s = carry + total;
    __syncthreads();
  }
}

__global__ __launch_bounds__(256) void scan_add_kernel(
    int* __restrict__ out, const int* __restrict__ bsum, int n)
{
  const int gid = blockIdx.x * 256 + threadIdx.x;
  if (gid < n) out[gid] += bsum[blockIdx.x];
}

__global__ __launch_bounds__(256) void scatter_kernel(
    const int* __restrict__ er, const int* __restrict__ ec,
    const float* __restrict__ ev, int* __restrict__ cursor,
    int* __restrict__ scols, float* __restrict__ svals, int E)
{
  int i = blockIdx.x * blockDim.x + threadIdx.x;
  const int stride = gridDim.x * blockDim.x;
  for (; i < E; i += stride) {
    const int r = er[i];
    const int pos = atomicAdd(&cursor[r], 1);
    scols[pos] = ec[i];
    svals[pos] = ev[i];
  }
}

// ---------------------------------------------------------------------------
// CSR SpMM: one wave per row, lane = output dim. Register accumulate, one
// plain store per row. Edge scalars through SGPR (readfirstlane), gathers
// 4-deep for memory-level parallelism. No atomics.
// ---------------------------------------------------------------------------
__global__ __launch_bounds__(256) void spmm_csr_kernel(
    const int* __restrict__ rowptr, const int* __restrict__ scols,
    const float* __restrict__ svals, const float* __restrict__ x,
    float* __restrict__ out, int N)
{
  const int lane = threadIdx.x & 63;
  const int row  = blockIdx.x * 4 + (threadIdx.x >> 6);
  if (row >= N) return;

  const int s = rowptr[row];
  const int e = rowptr[row + 1];
  float acc = 0.0f;

  int i = s;
  for (; i + 4 <= e; i += 4) {
    const int b = __builtin_amdgcn_readfirstlane(i);
    const int c0 = scols[b],     c1 = scols[b + 1];
    const int c2 = scols[b + 2], c3 = scols[b + 3];
    const float v0 = svals[b],     v1 = svals[b + 1];
    const float v2 = svals[b + 2], v3 = svals[b + 3];
    const float x0 = x[(size_t)c0 * DOUT + lane];
    const float x1 = x[(size_t)c1 * DOUT + lane];
    const float x2 = x[(size_t)c2 * DOUT + lane];
    const float x3 = x[(size_t)c3 * DOUT + lane];
    acc = fmaf(v0, x0, acc);
    acc = fmaf(v1, x1, acc);
    acc = fmaf(v2, x2, acc);
    acc = fmaf(v3, x3, acc);
  }
  for (; i < e; ++i) {
    const int b = __builtin_amdgcn_readfirstlane(i);
    acc = fmaf(svals[b], x[(size_t)scols[b] * DOUT + lane], acc);
  }

  out[(size_t)row * DOUT + lane] = acc;
}

// ---------------------------------------------------------------------------
// Launch. ws layout (floats/ints, 4B each):
//   sup    : N*64 f32          (25.6 MB)
//   rowptr : N+1 int
//   cursor : N+1 int   (doubles as histogram counts)
//   bsum   : 1024 int
//   scols  : E int             (6.4 MB)
//   svals  : E f32             (6.4 MB)
// ---------------------------------------------------------------------------
extern "C" void kernel_launch(void* const* d_in, const int* in_sizes, int n_in,
                              void* d_out, int out_size, void* d_ws, size_t ws_size,
                              hipStream_t stream)
{
  const float* X  = (const float*)d_in[0];
  const float* W  = (const float*)d_in[1];
  const int*   er = (const int*)d_in[2];
  const int*   ec = (const int*)d_in[3];
  const float* ev = (const float*)d_in[4];

  const int N = in_sizes[0] / DIN;
  const int E = in_sizes[2];
  const size_t half = (size_t)N * DOUT;

  char* w = (char*)d_ws;
  float* sup    = (float*)w;                 w += half * sizeof(float);
  int*   rowptr = (int*)w;                   w += (size_t)(N + 1) * sizeof(int);
  int*   cursor = (int*)w;                   w += (size_t)(N + 1) * sizeof(int);
  int*   bsum   = (int*)w;                   w += 1024 * sizeof(int);
  int*   scols  = (int*)w;                   w += (size_t)E * sizeof(int);
  float* svals  = (float*)w;

  float* out0 = (float*)d_out;               // output f32
  float* out1 = out0 + half;                 // az f32

  const int n_scan = N + 1;
  const int nb = (n_scan + 255) / 256;       // scan blocks (391 for N=100000)

  // ---- CSR build ----
  hipMemsetAsync(cursor, 0, (size_t)n_scan * sizeof(int), stream);
  hist_kernel<<<2048, 256, 0, stream>>>(er, cursor, E);
  scan_block_kernel<<<nb, 256, 0, stream>>>(cursor, rowptr, bsum, n_scan);
  scan_bsums_kernel<<<1, 256, 0, stream>>>(bsum, nb);
  scan_add_kernel<<<nb, 256, 0, stream>>>(rowptr, bsum, n_scan);
  hipMemcpyAsync(cursor, rowptr, (size_t)n_scan * sizeof(int),
                 hipMemcpyDeviceToDevice, stream);
  scatter_kernel<<<2048, 256, 0, stream>>>(er, ec, ev, cursor, scols, svals, E);

  // ---- support = leaky_relu(X @ W) ----
  gemm_lrelu_kernel<<<(N + 127) / 128, 256, 0, stream>>>(X, W, sup, N);

  // ---- output = A @ support ; az = A @ output (no atomics, full writes) ----
  spmm_csr_kernel<<<(N + 3) / 4, 256, 0, stream>>>(rowptr, scols, svals, sup, out0, N);
  spmm_csr_kernel<<<(N + 3) / 4, 256, 0, stream>>>(rowptr, scols, svals, out0, out1, N);
}

// Round 5
// 388.030 us; speedup vs baseline: 2.0849x; 1.1471x over previous
//
#include <hip/hip_runtime.h>
#include <hip/hip_bf16.h>

#define DIN 512
#define DOUT 64

typedef float float4v __attribute__((ext_vector_type(4)));
typedef float f32x4 __attribute__((ext_vector_type(4)));
typedef _Float16 f16x8 __attribute__((ext_vector_type(8)));
typedef unsigned int uint4v __attribute__((ext_vector_type(4)));

static __device__ __forceinline__ unsigned int pk_f16(float a, float b) {
  return __builtin_bit_cast(unsigned int, __builtin_amdgcn_cvt_pkrtz(a, b));
}

// ---------------------------------------------------------------------------
// Kernel 1: support = leaky_relu(X @ W, 0.2) via f16 MFMA (16x16x32).
// Block = 256 thr = 4 waves; block tile 64 rows x 64 cols (full DOUT).
// Wave w: rows [blk*64 + w*16, +16), all 64 cols (4 col-frags).
// A-frags: direct from global X (8 consecutive f32/lane -> cvt_pkrtz).
// B (W): staged per-256-K-half in LDS as packed f16 k-pairs [128][68] u32.
// Layouts (AMD lab notes, CDNA 16x16 family):
//   A: row = lane&15, k = (lane>>4)*8 + j
//   B: col = lane&15, k = (lane>>4)*8 + j
//   D: col = lane&15, row = (lane>>4)*4 + reg   [verified m89]
// ---------------------------------------------------------------------------
__global__ __launch_bounds__(256) void gemm_mfma_kernel(
    const float* __restrict__ X, const float* __restrict__ W,
    float* __restrict__ sup, int N)
{
  __shared__ unsigned int wlds[128][68];   // k-pairs x cols, +4 pad (34.8 KB)

  const int t    = threadIdx.x;
  const int wv   = t >> 6;
  const int lane = t & 63;
  const int l15  = lane & 15;
  const int g    = lane >> 4;

  const int rb   = blockIdx.x * 64 + wv * 16;
  const int rA   = rb + l15;
  const int rowA = rA < N ? rA : N - 1;                 // clamp loads
  const float* __restrict__ xrow = X + (size_t)rowA * DIN;

  f32x4 acc[4];
#pragma unroll
  for (int f = 0; f < 4; ++f) acc[f] = (f32x4)0.0f;

#pragma unroll 1
  for (int kh = 0; kh < 2; ++kh) {
    const int kbase = kh * 256;
    __syncthreads();
    // stage W[kbase..kbase+256) as f16 pairs: wlds[p][c] = {W[2p][c], W[2p+1][c]}
#pragma unroll
    for (int i = 0; i < 32; ++i) {
      const int idx = t + i * 256;
      const int c = idx & 63;
      const int p = idx >> 6;                           // 0..127
      const float w0 = W[(size_t)(kbase + 2 * p) * DOUT + c];
      const float w1 = W[(size_t)(kbase + 2 * p + 1) * DOUT + c];
      wlds[p][c] = pk_f16(w0, w1);
    }
    __syncthreads();

#pragma unroll
    for (int s = 0; s < 8; ++s) {
      const int k0 = kbase + s * 32;
      // A fragment: 8 consecutive f32 at xrow[k0 + g*8]
      const f32x4 a0 = *reinterpret_cast<const f32x4*>(xrow + k0 + g * 8);
      const f32x4 a1 = *reinterpret_cast<const f32x4*>(xrow + k0 + g * 8 + 4);
      uint4v au;
      au[0] = pk_f16(a0[0], a0[1]);
      au[1] = pk_f16(a0[2], a0[3]);
      au[2] = pk_f16(a1[0], a1[1]);
      au[3] = pk_f16(a1[2], a1[3]);
      const f16x8 afrag = __builtin_bit_cast(f16x8, au);

      const int pb = s * 16 + g * 4;                    // pair base in half
#pragma unroll
      for (int f = 0; f < 4; ++f) {
        const int c = f * 16 + l15;
        uint4v bu;
        bu[0] = wlds[pb + 0][c];
        bu[1] = wlds[pb + 1][c];
        bu[2] = wlds[pb + 2][c];
        bu[3] = wlds[pb + 3][c];
        const f16x8 bfrag = __builtin_bit_cast(f16x8, bu);
        acc[f] = __builtin_amdgcn_mfma_f32_16x16x32_f16(afrag, bfrag, acc[f], 0, 0, 0);
      }
    }
  }

  // epilogue: leaky_relu + store. D: row = g*4+reg, col = f*16+l15
  const int r0 = rb + g * 4;
#pragma unroll
  for (int f = 0; f < 4; ++f) {
    const int c = f * 16 + l15;
#pragma unroll
    for (int reg = 0; reg < 4; ++reg) {
      const int r = r0 + reg;
      if (r < N) {
        const float v = acc[f][reg];
        sup[(size_t)r * DOUT + c] = v > 0.0f ? v : 0.2f * v;
      }
    }
  }
}

// ---------------------------------------------------------------------------
// CSR build: histogram -> exclusive scan (3 kernels) -> scatter  [unchanged]
// ---------------------------------------------------------------------------
__global__ __launch_bounds__(256) void hist_kernel(
    const int* __restrict__ er, int* __restrict__ cnt, int E)
{
  int i = blockIdx.x * blockDim.x + threadIdx.x;
  const int stride = gridDim.x * blockDim.x;
  for (; i < E; i += stride) atomicAdd(&cnt[er[i]], 1);
}

__global__ __launch_bounds__(256) void scan_block_kernel(
    const int* __restrict__ in, int* __restrict__ out,
    int* __restrict__ bsum, int n)
{
  __shared__ int s[256];
  const int t = threadIdx.x;
  const int gid = blockIdx.x * 256 + t;
  const int v = gid < n ? in[gid] : 0;
  s[t] = v;
  __syncthreads();
#pragma unroll
  for (int off = 1; off < 256; off <<= 1) {
    const int add = t >= off ? s[t - off] : 0;
    __syncthreads();
    s[t] += add;
    __syncthreads();
  }
  if (gid < n) out[gid] = s[t] - v;
  if (t == 255) bsum[blockIdx.x] = s[255];
}

__global__ __launch_bounds__(256) void scan_bsums_kernel(int* __restrict__ bsum, int nb)
{
  __shared__ int s[256];
  __shared__ int carry_s;
  const int t = threadIdx.x;
  if (t == 0) carry_s = 0;
  __syncthreads();
  for (int base = 0; base < nb; base += 256) {
    const int i = base + t;
    const int v = i < nb ? bsum[i] : 0;
    s[t] = v;
    __syncthreads();
#pragma unroll
    for (int off = 1; off < 256; off <<= 1) {
      const int add = t >= off ? s[t - off] : 0;
      __syncthreads();
      s[t] += add;
      __syncthreads();
    }
    const int carry = carry_s;
    if (i < nb) bsum[i] = s[t] - v + carry;
    const int total = s[255];
    __syncthreads();
    if (t == 0) carry_s = carry + total;
    __syncthreads();
  }
}

__global__ __launch_bounds__(256) void scan_add_kernel(
    int* __restrict__ out, const int* __restrict__ bsum, int n)
{
  const int gid = blockIdx.x * 256 + threadIdx.x;
  if (gid < n) out[gid] += bsum[blockIdx.x];
}

__global__ __launch_bounds__(256) void scatter_kernel(
    const int* __restrict__ er, const int* __restrict__ ec,
    const float* __restrict__ ev, int* __restrict__ cursor,
    int* __restrict__ scols, float* __restrict__ svals, int E)
{
  int i = blockIdx.x * blockDim.x + threadIdx.x;
  const int stride = gridDim.x * blockDim.x;
  for (; i < E; i += stride) {
    const int r = er[i];
    const int pos = atomicAdd(&cursor[r], 1);
    scols[pos] = ec[i];
    svals[pos] = ev[i];
  }
}

// ---------------------------------------------------------------------------
// CSR SpMM: one wave per row, lane = output dim  [unchanged]
// ---------------------------------------------------------------------------
__global__ __launch_bounds__(256) void spmm_csr_kernel(
    const int* __restrict__ rowptr, const int* __restrict__ scols,
    const float* __restrict__ svals, const float* __restrict__ x,
    float* __restrict__ out, int N)
{
  const int lane = threadIdx.x & 63;
  const int row  = blockIdx.x * 4 + (threadIdx.x >> 6);
  if (row >= N) return;

  const int s = rowptr[row];
  const int e = rowptr[row + 1];
  float acc = 0.0f;

  int i = s;
  for (; i + 4 <= e; i += 4) {
    const int b = __builtin_amdgcn_readfirstlane(i);
    const int c0 = scols[b],     c1 = scols[b + 1];
    const int c2 = scols[b + 2], c3 = scols[b + 3];
    const float v0 = svals[b],     v1 = svals[b + 1];
    const float v2 = svals[b + 2], v3 = svals[b + 3];
    const float x0 = x[(size_t)c0 * DOUT + lane];
    const float x1 = x[(size_t)c1 * DOUT + lane];
    const float x2 = x[(size_t)c2 * DOUT + lane];
    const float x3 = x[(size_t)c3 * DOUT + lane];
    acc = fmaf(v0, x0, acc);
    acc = fmaf(v1, x1, acc);
    acc = fmaf(v2, x2, acc);
    acc = fmaf(v3, x3, acc);
  }
  for (; i < e; ++i) {
    const int b = __builtin_amdgcn_readfirstlane(i);
    acc = fmaf(svals[b], x[(size_t)scols[b] * DOUT + lane], acc);
  }

  out[(size_t)row * DOUT + lane] = acc;
}

// ---------------------------------------------------------------------------
// Launch
// ---------------------------------------------------------------------------
extern "C" void kernel_launch(void* const* d_in, const int* in_sizes, int n_in,
                              void* d_out, int out_size, void* d_ws, size_t ws_size,
                              hipStream_t stream)
{
  const float* X  = (const float*)d_in[0];
  const float* W  = (const float*)d_in[1];
  const int*   er = (const int*)d_in[2];
  const int*   ec = (const int*)d_in[3];
  const float* ev = (const float*)d_in[4];

  const int N = in_sizes[0] / DIN;
  const int E = in_sizes[2];
  const size_t half = (size_t)N * DOUT;

  char* w = (char*)d_ws;
  float* sup    = (float*)w;                 w += half * sizeof(float);
  int*   rowptr = (int*)w;                   w += (size_t)(N + 1) * sizeof(int);
  int*   cursor = (int*)w;                   w += (size_t)(N + 1) * sizeof(int);
  int*   bsum   = (int*)w;                   w += 1024 * sizeof(int);
  int*   scols  = (int*)w;                   w += (size_t)E * sizeof(int);
  float* svals  = (float*)w;

  float* out0 = (float*)d_out;
  float* out1 = out0 + half;

  const int n_scan = N + 1;
  const int nb = (n_scan + 255) / 256;

  // ---- CSR build ----
  (void)hipMemsetAsync(cursor, 0, (size_t)n_scan * sizeof(int), stream);
  hist_kernel<<<2048, 256, 0, stream>>>(er, cursor, E);
  scan_block_kernel<<<nb, 256, 0, stream>>>(cursor, rowptr, bsum, n_scan);
  scan_bsums_kernel<<<1, 256, 0, stream>>>(bsum, nb);
  scan_add_kernel<<<nb, 256, 0, stream>>>(rowptr, bsum, n_scan);
  (void)hipMemcpyAsync(cursor, rowptr, (size_t)n_scan * sizeof(int),
                       hipMemcpyDeviceToDevice, stream);
  scatter_kernel<<<2048, 256, 0, stream>>>(er, ec, ev, cursor, scols, svals, E);

  // ---- support = leaky_relu(X @ W) via MFMA ----
  gemm_mfma_kernel<<<(N + 63) / 64, 256, 0, stream>>>(X, W, sup, N);

  // ---- output = A @ support ; az = A @ output ----
  spmm_csr_kernel<<<(N + 3) / 4, 256, 0, stream>>>(rowptr, scols, svals, sup, out0, N);
  spmm_csr_kernel<<<(N + 3) / 4, 256, 0, stream>>>(rowptr, scols, svals, out0, out1, N);
}

// Round 6
// 362.484 us; speedup vs baseline: 2.2318x; 1.0705x over previous
//
#include <hip/hip_runtime.h>
#include <hip/hip_bf16.h>

#define DIN 512
#define DOUT 64

typedef float f32x4 __attribute__((ext_vector_type(4)));
typedef _Float16 f16x8 __attribute__((ext_vector_type(8)));
typedef unsigned int uint4v __attribute__((ext_vector_type(4)));

static __device__ __forceinline__ unsigned int pk_f16(float a, float b) {
  return __builtin_bit_cast(unsigned int, __builtin_amdgcn_cvt_pkrtz(a, b));
}

// ---------------------------------------------------------------------------
// Kernel 0: pre-pack W (f32 [512][64]) -> pw (u32 [64][256]):
//   pw[c][p] = {f16(W[2p][c]), f16(W[2p+1][c])}  (transposed, k-pairs packed)
// Runs once per launch, ~128 KB read / 64 KB write.
// ---------------------------------------------------------------------------
__global__ __launch_bounds__(256) void pack_w_kernel(
    const float* __restrict__ W, unsigned int* __restrict__ pw)
{
  const int idx = blockIdx.x * 256 + threadIdx.x;   // 0..16383
  const int c = idx >> 8;
  const int p = idx & 255;
  pw[idx] = pk_f16(W[(size_t)(2 * p) * DOUT + c],
                   W[(size_t)(2 * p + 1) * DOUT + c]);
}

// ---------------------------------------------------------------------------
// Kernel 1: support = leaky_relu(X @ W, 0.2) via f16 MFMA (16x16x32).
// Same tiling as round 5 (validated: 64 rows x 64 cols / block, 4 waves).
// Changes for latency:
//  - all 16 A dwordx4 loads of a K-half issued before any use (MLP 16)
//  - B staged from pre-packed pw as straight 16B copies
//  - LDS layout [col][pair] (+4 pad -> 132) so B frag = 1x ds_read_b128
// ---------------------------------------------------------------------------
__global__ __launch_bounds__(256) void gemm_mfma_kernel(
    const float* __restrict__ X, const unsigned int* __restrict__ pw,
    float* __restrict__ sup, int N)
{
  __shared__ unsigned int wlds[64][132];   // cols x k-pairs(half), 33.8 KB

  const int t    = threadIdx.x;
  const int wv   = t >> 6;
  const int lane = t & 63;
  const int l15  = lane & 15;
  const int g    = lane >> 4;

  const int rb   = blockIdx.x * 64 + wv * 16;
  const int rA   = rb + l15;
  const int rowA = rA < N ? rA : N - 1;                 // clamp loads
  const float* __restrict__ xrow = X + (size_t)rowA * DIN;

  // staging map: thread t copies pw[c][kh*128 + q*32 .. +32) -> wlds[c][q*32..]
  const int sc = t >> 2;
  const int sq = t & 3;

  f32x4 acc[4];
#pragma unroll
  for (int f = 0; f < 4; ++f) acc[f] = (f32x4)0.0f;

#pragma unroll 1
  for (int kh = 0; kh < 2; ++kh) {
    const int kbase = kh * 256;

    // ---- issue ALL A loads for this K-half (16 dwordx4 in flight) ----
    f32x4 a[16];
#pragma unroll
    for (int s = 0; s < 8; ++s) {
      a[2 * s]     = *reinterpret_cast<const f32x4*>(xrow + kbase + s * 32 + g * 8);
      a[2 * s + 1] = *reinterpret_cast<const f32x4*>(xrow + kbase + s * 32 + g * 8 + 4);
    }

    // ---- stage W half: contiguous 16B copies ----
    __syncthreads();
    {
      const unsigned int* __restrict__ src = pw + sc * 256 + kh * 128 + sq * 32;
      uint4v* __restrict__ dst = reinterpret_cast<uint4v*>(&wlds[sc][sq * 32]);
#pragma unroll
      for (int i = 0; i < 8; ++i)
        dst[i] = *(reinterpret_cast<const uint4v*>(src) + i);
    }
    __syncthreads();

    // ---- compute ----
#pragma unroll
    for (int s = 0; s < 8; ++s) {
      uint4v au;
      au[0] = pk_f16(a[2 * s][0], a[2 * s][1]);
      au[1] = pk_f16(a[2 * s][2], a[2 * s][3]);
      au[2] = pk_f16(a[2 * s + 1][0], a[2 * s + 1][1]);
      au[3] = pk_f16(a[2 * s + 1][2], a[2 * s + 1][3]);
      const f16x8 afrag = __builtin_bit_cast(f16x8, au);

      const int pb = s * 16 + g * 4;                    // pair base in half
#pragma unroll
      for (int f = 0; f < 4; ++f) {
        const int c = f * 16 + l15;
        const uint4v bu = *reinterpret_cast<const uint4v*>(&wlds[c][pb]);
        const f16x8 bfrag = __builtin_bit_cast(f16x8, bu);
        acc[f] = __builtin_amdgcn_mfma_f32_16x16x32_f16(afrag, bfrag, acc[f], 0, 0, 0);
      }
    }
  }

  // epilogue: leaky_relu + store. D: row = g*4+reg, col = f*16+l15
  const int r0 = rb + g * 4;
#pragma unroll
  for (int f = 0; f < 4; ++f) {
    const int c = f * 16 + l15;
#pragma unroll
    for (int reg = 0; reg < 4; ++reg) {
      const int r = r0 + reg;
      if (r < N) {
        const float v = acc[f][reg];
        sup[(size_t)r * DOUT + c] = v > 0.0f ? v : 0.2f * v;
      }
    }
  }
}

// ---------------------------------------------------------------------------
// CSR build: histogram -> exclusive scan (3 kernels) -> scatter  [unchanged]
// ---------------------------------------------------------------------------
__global__ __launch_bounds__(256) void hist_kernel(
    const int* __restrict__ er, int* __restrict__ cnt, int E)
{
  int i = blockIdx.x * blockDim.x + threadIdx.x;
  const int stride = gridDim.x * blockDim.x;
  for (; i < E; i += stride) atomicAdd(&cnt[er[i]], 1);
}

__global__ __launch_bounds__(256) void scan_block_kernel(
    const int* __restrict__ in, int* __restrict__ out,
    int* __restrict__ bsum, int n)
{
  __shared__ int s[256];
  const int t = threadIdx.x;
  const int gid = blockIdx.x * 256 + t;
  const int v = gid < n ? in[gid] : 0;
  s[t] = v;
  __syncthreads();
#pragma unroll
  for (int off = 1; off < 256; off <<= 1) {
    const int add = t >= off ? s[t - off] : 0;
    __syncthreads();
    s[t] += add;
    __syncthreads();
  }
  if (gid < n) out[gid] = s[t] - v;
  if (t == 255) bsum[blockIdx.x] = s[255];
}

__global__ __launch_bounds__(256) void scan_bsums_kernel(int* __restrict__ bsum, int nb)
{
  __shared__ int s[256];
  __shared__ int carry_s;
  const int t = threadIdx.x;
  if (t == 0) carry_s = 0;
  __syncthreads();
  for (int base = 0; base < nb; base += 256) {
    const int i = base + t;
    const int v = i < nb ? bsum[i] : 0;
    s[t] = v;
    __syncthreads();
#pragma unroll
    for (int off = 1; off < 256; off <<= 1) {
      const int add = t >= off ? s[t - off] : 0;
      __syncthreads();
      s[t] += add;
      __syncthreads();
    }
    const int carry = carry_s;
    if (i < nb) bsum[i] = s[t] - v + carry;
    const int total = s[255];
    __syncthreads();
    if (t == 0) carry_s = carry + total;
    __syncthreads();
  }
}

__global__ __launch_bounds__(256) void scan_add_kernel(
    int* __restrict__ out, const int* __restrict__ bsum, int n)
{
  const int gid = blockIdx.x * 256 + threadIdx.x;
  if (gid < n) out[gid] += bsum[blockIdx.x];
}

__global__ __launch_bounds__(256) void scatter_kernel(
    const int* __restrict__ er, const int* __restrict__ ec,
    const float* __restrict__ ev, int* __restrict__ cursor,
    int* __restrict__ scols, float* __restrict__ svals, int E)
{
  int i = blockIdx.x * blockDim.x + threadIdx.x;
  const int stride = gridDim.x * blockDim.x;
  for (; i < E; i += stride) {
    const int r = er[i];
    const int pos = atomicAdd(&cursor[r], 1);
    scols[pos] = ec[i];
    svals[pos] = ev[i];
  }
}

// ---------------------------------------------------------------------------
// CSR SpMM: one wave per row, lane = output dim. 8-deep gather unroll for MLP.
// ---------------------------------------------------------------------------
__global__ __launch_bounds__(256) void spmm_csr_kernel(
    const int* __restrict__ rowptr, const int* __restrict__ scols,
    const float* __restrict__ svals, const float* __restrict__ x,
    float* __restrict__ out, int N)
{
  const int lane = threadIdx.x & 63;
  const int row  = blockIdx.x * 4 + (threadIdx.x >> 6);
  if (row >= N) return;

  const int s = rowptr[row];
  const int e = rowptr[row + 1];
  float acc = 0.0f;

  int i = s;
  for (; i + 8 <= e; i += 8) {
    const int b = __builtin_amdgcn_readfirstlane(i);
    int   cc[8];
    float vv[8];
    float xx[8];
#pragma unroll
    for (int j = 0; j < 8; ++j) cc[j] = scols[b + j];
#pragma unroll
    for (int j = 0; j < 8; ++j) vv[j] = svals[b + j];
#pragma unroll
    for (int j = 0; j < 8; ++j) xx[j] = x[(size_t)cc[j] * DOUT + lane];
#pragma unroll
    for (int j = 0; j < 8; ++j) acc = fmaf(vv[j], xx[j], acc);
  }
  for (; i + 4 <= e; i += 4) {
    const int b = __builtin_amdgcn_readfirstlane(i);
    const int c0 = scols[b],     c1 = scols[b + 1];
    const int c2 = scols[b + 2], c3 = scols[b + 3];
    const float v0 = svals[b],     v1 = svals[b + 1];
    const float v2 = svals[b + 2], v3 = svals[b + 3];
    const float x0 = x[(size_t)c0 * DOUT + lane];
    const float x1 = x[(size_t)c1 * DOUT + lane];
    const float x2 = x[(size_t)c2 * DOUT + lane];
    const float x3 = x[(size_t)c3 * DOUT + lane];
    acc = fmaf(v0, x0, acc);
    acc = fmaf(v1, x1, acc);
    acc = fmaf(v2, x2, acc);
    acc = fmaf(v3, x3, acc);
  }
  for (; i < e; ++i) {
    const int b = __builtin_amdgcn_readfirstlane(i);
    acc = fmaf(svals[b], x[(size_t)scols[b] * DOUT + lane], acc);
  }

  out[(size_t)row * DOUT + lane] = acc;
}

// ---------------------------------------------------------------------------
// Launch. ws layout:
//   sup    : N*64 f32          (25.6 MB)
//   rowptr : N+1 int
//   cursor : N+1 int
//   bsum   : 1024 int
//   scols  : E int             (6.4 MB)
//   svals  : E f32             (6.4 MB)
//   pw     : 64*256 u32        (64 KB, packed f16 W)
// ---------------------------------------------------------------------------
extern "C" void kernel_launch(void* const* d_in, const int* in_sizes, int n_in,
                              void* d_out, int out_size, void* d_ws, size_t ws_size,
                              hipStream_t stream)
{
  const float* X  = (const float*)d_in[0];
  const float* W  = (const float*)d_in[1];
  const int*   er = (const int*)d_in[2];
  const int*   ec = (const int*)d_in[3];
  const float* ev = (const float*)d_in[4];

  const int N = in_sizes[0] / DIN;
  const int E = in_sizes[2];
  const size_t half = (size_t)N * DOUT;

  char* w = (char*)d_ws;
  float* sup    = (float*)w;                 w += half * sizeof(float);
  int*   rowptr = (int*)w;                   w += (size_t)(N + 1) * sizeof(int);
  int*   cursor = (int*)w;                   w += (size_t)(N + 1) * sizeof(int);
  int*   bsum   = (int*)w;                   w += 1024 * sizeof(int);
  int*   scols  = (int*)w;                   w += (size_t)E * sizeof(int);
  float* svals  = (float*)w;                 w += (size_t)E * sizeof(float);
  unsigned int* pw = (unsigned int*)w;

  float* out0 = (float*)d_out;
  float* out1 = out0 + half;

  const int n_scan = N + 1;
  const int nb = (n_scan + 255) / 256;

  // ---- CSR build ----
  (void)hipMemsetAsync(cursor, 0, (size_t)n_scan * sizeof(int), stream);
  hist_kernel<<<2048, 256, 0, stream>>>(er, cursor, E);
  scan_block_kernel<<<nb, 256, 0, stream>>>(cursor, rowptr, bsum, n_scan);
  scan_bsums_kernel<<<1, 256, 0, stream>>>(bsum, nb);
  scan_add_kernel<<<nb, 256, 0, stream>>>(rowptr, bsum, n_scan);
  (void)hipMemcpyAsync(cursor, rowptr, (size_t)n_scan * sizeof(int),
                       hipMemcpyDeviceToDevice, stream);
  scatter_kernel<<<2048, 256, 0, stream>>>(er, ec, ev, cursor, scols, svals, E);

  // ---- W pre-pack + support = leaky_relu(X @ W) via MFMA ----
  pack_w_kernel<<<64, 256, 0, stream>>>(W, pw);
  gemm_mfma_kernel<<<(N + 63) / 64, 256, 0, stream>>>(X, pw, sup, N);

  // ---- output = A @ support ; az = A @ output ----
  spmm_csr_kernel<<<(N + 3) / 4, 256, 0, stream>>>(rowptr, scols, svals, sup, out0, N);
  spmm_csr_kernel<<<(N + 3) / 4, 256, 0, stream>>>(rowptr, scols, svals, out0, out1, N);
}